// Round 6
// baseline (545.028 us; speedup 1.0000x reference)
//
#include <hip/hip_runtime.h>
#include <hip/hip_fp16.h>
#include <hip/hip_cooperative_groups.h>

namespace cg = cooperative_groups;

#define FD 96        // feature dim
#define COL_CAP 2048 // LDS col staging capacity (32 rows, avg ~18 edges; only
                     // the block containing HUB (~50K edges) overflows)

typedef _Float16 f16x8 __attribute__((ext_vector_type(8)));
typedef float f32x4 __attribute__((ext_vector_type(4)));

// ---- fp16 pack/unpack helpers ---------------------------------------------
__device__ inline float2 unpack2(int v) {
    __half2 h = *reinterpret_cast<__half2*>(&v);
    return __half22float2(h);
}
__device__ inline int2 pack4(float a, float b, float c, float d) {
    __half2 lo = __floats2half2_rn(a, b);
    __half2 hi = __floats2half2_rn(c, d);
    int2 r;
    r.x = *reinterpret_cast<int*>(&lo);
    r.y = *reinterpret_cast<int*>(&hi);
    return r;
}
// pack 8 fp32 -> f16x8 with pack4 rounding (== pack_hub path)
__device__ inline f16x8 pack8h(const float* __restrict__ h) {
    int2 a = pack4(h[0], h[1], h[2], h[3]);
    int2 b = pack4(h[4], h[5], h[6], h[7]);
    int4 r = make_int4(a.x, a.y, b.x, b.y);
    return *reinterpret_cast<f16x8*>(&r);
}
// load 4 fp16 (int2) from LDS -> float4
__device__ inline float4 lds_w4(const __half* Wl, int k, int c4) {
    int2 wv = *(const int2*)&Wl[k * FD + c4];
    float2 lo = unpack2(wv.x), hi = unpack2(wv.y);
    return make_float4(lo.x, lo.y, hi.x, hi.y);
}

// ---- 8-unroll aggregation over a HALF-TABLE (stride 12 int2 per row).
// c in 0..11 selects the 4-feature group; arithmetic order identical to the
// verified round-0/round-4 pull kernels. COLX(e) supplies the source index.
#define AGG12_BODY(COLX)                                                      \
    float ax = 0.f, ay = 0.f, az = 0.f, aw = 0.f;                             \
    int e = beg;                                                              \
    for (; e + 8 <= end; e += 8) {                                            \
        int s0 = COLX(e + 0), s1 = COLX(e + 1), s2 = COLX(e + 2), s3 = COLX(e + 3); \
        int s4 = COLX(e + 4), s5 = COLX(e + 5), s6 = COLX(e + 6), s7 = COLX(e + 7); \
        int2 r0 = fh[(long)s0 * 12 + c], r1 = fh[(long)s1 * 12 + c];          \
        int2 r2 = fh[(long)s2 * 12 + c], r3 = fh[(long)s3 * 12 + c];          \
        int2 r4 = fh[(long)s4 * 12 + c], r5 = fh[(long)s5 * 12 + c];          \
        int2 r6 = fh[(long)s6 * 12 + c], r7 = fh[(long)s7 * 12 + c];          \
        float2 l0 = unpack2(r0.x), h0 = unpack2(r0.y);                        \
        float2 l1 = unpack2(r1.x), h1_ = unpack2(r1.y);                       \
        float2 l2 = unpack2(r2.x), h2 = unpack2(r2.y);                        \
        float2 l3 = unpack2(r3.x), h3 = unpack2(r3.y);                        \
        float2 l4 = unpack2(r4.x), h4 = unpack2(r4.y);                        \
        float2 l5 = unpack2(r5.x), h5 = unpack2(r5.y);                        \
        float2 l6 = unpack2(r6.x), h6 = unpack2(r6.y);                        \
        float2 l7 = unpack2(r7.x), h7 = unpack2(r7.y);                        \
        ax += (l0.x + l1.x) + (l2.x + l3.x) + (l4.x + l5.x) + (l6.x + l7.x);  \
        ay += (l0.y + l1.y) + (l2.y + l3.y) + (l4.y + l5.y) + (l6.y + l7.y);  \
        az += (h0.x + h1_.x) + (h2.x + h3.x) + (h4.x + h5.x) + (h6.x + h7.x); \
        aw += (h0.y + h1_.y) + (h2.y + h3.y) + (h4.y + h5.y) + (h6.y + h7.y); \
    }                                                                         \
    for (; e < end; e++) {                                                    \
        int s = COLX(e);                                                      \
        int2 r = fh[(long)s * 12 + c];                                        \
        float2 lo = unpack2(r.x), hi = unpack2(r.y);                          \
        ax += lo.x; ay += lo.y; az += hi.x; aw += hi.y;                       \
    }

__device__ inline float4 agg12_glb(const int2* __restrict__ fh,
                                   const int* __restrict__ col,
                                   int beg, int end, int c) {
    #define COLG(E) col[E]
    AGG12_BODY(COLG)
    #undef COLG
    return make_float4(ax, ay, az, aw);
}
__device__ inline float4 agg12_lds(const int2* __restrict__ fh,
                                   const int* colS, int beg, int end, int c) {
    #define COLS(E) colS[E]
    AGG12_BODY(COLS)
    #undef COLS
    return make_float4(ax, ay, az, aw);
}

// ---------------------------------------------------------------------------
// build_coop: cooperative mega-kernel replacing {memset, deg, scan, prep}.
// 256 blocks x 1024 thr (1 block/CU -> co-residency guaranteed). Phases
// separated by grid.sync(); each phase's arithmetic identical to the
// verified split kernels.
//   P0: zero counts[N], hubacc[FD], a0hub[FD]
//   P1: deg histogram + perm rank capture (ballot hub path)
//   P2: scan -> rowptr[0..N] + dinv (blocks 0..NB-1, same block code)
//   P3: CSR col fill + xh halves convert + Wt convert
// ---------------------------------------------------------------------------
__global__ __launch_bounds__(1024, 8)
void build_coop(const int* __restrict__ src, const int* __restrict__ dst, int E,
                const float* __restrict__ x, int N, int HUB,
                const float* __restrict__ W2a, const float* __restrict__ W2b,
                int* __restrict__ counts, int* __restrict__ perm,
                int* __restrict__ rowptr, float* __restrict__ dinv,
                int* __restrict__ col,
                int2* __restrict__ xhL, int2* __restrict__ xhH,
                __half* __restrict__ Wta, __half* __restrict__ Wtb,
                float* __restrict__ hubacc, float* __restrict__ a0hub) {
    cg::grid_group grid = cg::this_grid();
    const int T  = gridDim.x * 1024;
    const int gt = blockIdx.x * 1024 + threadIdx.x;

    // ---- P0: zero ----
    for (int i = gt; i < N; i += T) counts[i] = 0;
    for (int i = gt; i < FD; i += T) { hubacc[i] = 0.f; a0hub[i] = 0.f; }
    __threadfence();
    grid.sync();

    // ---- P1: deg ----
    int Er = (E + 63) & ~63;
    for (int e = gt; e < Er; e += T) {
        int d = (e < E) ? dst[e] : -1;
        bool isHub = (d == HUB);
        unsigned long long m = __ballot(isHub);
        if (isHub) {
            int lane = threadIdx.x & 63;
            int leader = __ffsll((unsigned long long)m) - 1;
            int base = 0;
            if (lane == leader) base = atomicAdd(&counts[HUB], (int)__popcll(m));
            base = __shfl(base, leader);
            unsigned long long below = m & ((1ull << lane) - 1ull);
            perm[e] = base + (int)__popcll(below);
        } else if (d >= 0) {
            perm[e] = atomicAdd(&counts[d], 1);
        }
    }
    __threadfence();
    grid.sync();

    // ---- P2: scan (blocks 0..NB-1, identical to scan_kernel) ----
    __shared__ int wsA[16];
    __shared__ int preS;
    __shared__ int wsum[16];
    int NB = (N + 1023) / 1024;
    if ((int)blockIdx.x < NB) {
        int t = threadIdx.x, lane = t & 63, wv = t >> 6;
        int base = blockIdx.x * 1024;
        int pre = 0;
        for (int idx = t; idx < base; idx += 1024) pre += counts[idx];
        #pragma unroll
        for (int off = 32; off; off >>= 1) pre += __shfl_down(pre, off);
        if (lane == 0) wsA[wv] = pre;
        __syncthreads();
        if (t == 0) {
            int s = 0;
            #pragma unroll
            for (int k = 0; k < 16; k++) s += wsA[k];
            preS = s;
        }
        __syncthreads();
        int blockpre = preS;
        int i = base + t;
        int v = (i < N) ? counts[i] : 0;
        int xx = v;
        #pragma unroll
        for (int off = 1; off < 64; off <<= 1) {
            int u = __shfl_up(xx, off);
            if (lane >= off) xx += u;
        }
        if (lane == 63) wsum[wv] = xx;
        __syncthreads();
        if (wv == 0 && lane < 16) {
            int w = wsum[lane];
            #pragma unroll
            for (int off = 1; off < 16; off <<= 1) {
                int u = __shfl_up(w, off);
                if (lane >= off) w += u;
            }
            wsum[lane] = w;
        }
        __syncthreads();
        int waveoff = (wv == 0) ? 0 : wsum[wv - 1];
        if (i <= N) rowptr[i] = blockpre + waveoff + xx - v;
        if (i < N) {
            float d = (float)v;
            dinv[i] = (d > 0.f) ? rsqrtf(fmaxf(d, 1.f)) : 0.f;
        }
    }
    __threadfence();
    grid.sync();

    // ---- P3: prep ----
    for (int e = gt; e < E; e += T) {
        int d = dst[e];
        col[rowptr[d] + perm[e]] = src[e];
    }
    for (int i = gt; i < N * 24; i += T) {
        int n = i / 24, g = i % 24;
        float dn = dinv[n];
        float4 a = ((const float4*)x)[i];
        int2 v = pack4(a.x * dn, a.y * dn, a.z * dn, a.w * dn);
        if (g < 12) xhL[(long)n * 12 + g] = v;
        else        xhH[(long)n * 12 + g - 12] = v;
    }
    for (int i = gt; i < FD * FD; i += T) {
        int n = i / FD, k = i % FD;
        Wta[i] = __float2half(W2a[k * FD + n]);
        Wtb[i] = __float2half(W2b[k * FD + n]);
    }
}

// ---------------------------------------------------------------------------
// Merged half-table pull+hub kernels. Grid = 2*G + 128; block 384 = (c 0..11,
// y 0..31). Unchanged from round 5 (verified).
// ---------------------------------------------------------------------------
__global__ __launch_bounds__(384)
void pull_hub32(const int2* __restrict__ fhL, const int2* __restrict__ fhH,
                const float* __restrict__ dinv,
                const int* __restrict__ rowptr, const int* __restrict__ col,
                int N, int HUB, int G,
                float* __restrict__ out, float* __restrict__ hubdest) {
    __shared__ int colS[COL_CAP];
    __shared__ float4 red[32][12];
    int t = threadIdx.x;
    int c = t % 12, y = t / 12;
    int b = blockIdx.x;
    if (b < 2 * G) {
        const int2* fh = (b < G) ? fhL : fhH;
        int foff = (b < G) ? 0 : 12;
        int bb = (b < G) ? b : b - G;
        int n0 = bb * 32;
        int nend = min(n0 + 32, N);
        int beg0 = rowptr[n0];
        int span = rowptr[nend] - beg0;
        bool staged = (span <= COL_CAP);
        if (staged) {
            for (int i = t; i < span; i += 384) colS[i] = col[beg0 + i];
            __syncthreads();
        }
        int n = n0 + y;
        if (n < N && n != HUB) {
            int beg = rowptr[n], end = rowptr[n + 1];
            float4 a = staged ? agg12_lds(fh, colS, beg - beg0, end - beg0, c)
                              : agg12_glb(fh, col, beg, end, c);
            float dn = dinv[n];
            ((float4*)out)[(long)n * 24 + foff + c] =
                make_float4(a.x * dn, a.y * dn, a.z * dn, a.w * dn);
        }
    } else {
        int hb = b - 2 * G;
        const int2* fh = (hb < 64) ? fhL : fhH;
        int foff = (hb < 64) ? 0 : 12;
        int bb = (hb < 64) ? hb : hb - 64;
        int beg = rowptr[HUB], end = rowptr[HUB + 1];
        int deg = end - beg;
        int chunk = (deg + 2047) / 2048;
        int sid = bb * 32 + y;
        int e = beg + sid * chunk;
        int e1 = min(e + chunk, end);
        float ax = 0.f, ay = 0.f, az = 0.f, aw = 0.f;
        for (; e + 4 <= e1; e += 4) {
            int s0 = col[e + 0], s1 = col[e + 1], s2 = col[e + 2], s3 = col[e + 3];
            int2 r0 = fh[(long)s0 * 12 + c], r1 = fh[(long)s1 * 12 + c];
            int2 r2 = fh[(long)s2 * 12 + c], r3 = fh[(long)s3 * 12 + c];
            float2 l0 = unpack2(r0.x), h0 = unpack2(r0.y);
            float2 l1 = unpack2(r1.x), h1_ = unpack2(r1.y);
            float2 l2 = unpack2(r2.x), h2 = unpack2(r2.y);
            float2 l3 = unpack2(r3.x), h3 = unpack2(r3.y);
            ax += (l0.x + l1.x) + (l2.x + l3.x);
            ay += (l0.y + l1.y) + (l2.y + l3.y);
            az += (h0.x + h1_.x) + (h2.x + h3.x);
            aw += (h0.y + h1_.y) + (h2.y + h3.y);
        }
        for (; e < e1; e++) {
            int s = col[e];
            int2 r = fh[(long)s * 12 + c];
            float2 lo = unpack2(r.x), hi = unpack2(r.y);
            ax += lo.x; ay += lo.y; az += hi.x; aw += hi.y;
        }
        red[y][c] = make_float4(ax, ay, az, aw);
        __syncthreads();
        if (y == 0) {
            float4 tt = red[0][c];
            #pragma unroll
            for (int k = 1; k < 32; k++) {
                float4 u = red[k][c];
                tt.x += u.x; tt.y += u.y; tt.z += u.z; tt.w += u.w;
            }
            float dh = dinv[HUB];
            float* o = hubdest + (foff + c) * 4;
            unsafeAtomicAdd(o + 0, tt.x * dh);
            unsafeAtomicAdd(o + 1, tt.y * dh);
            unsafeAtomicAdd(o + 2, tt.z * dh);
            unsafeAtomicAdd(o + 3, tt.w * dh);
        }
    }
}

__global__ __launch_bounds__(384)
void pull_hub16(const int2* __restrict__ fhL, const int2* __restrict__ fhH,
                const float* __restrict__ dinv,
                const int* __restrict__ rowptr, const int* __restrict__ col,
                int N, int HUB, int G,
                int2* __restrict__ out16, float* __restrict__ hubdest) {
    __shared__ int colS[COL_CAP];
    __shared__ float4 red[32][12];
    int t = threadIdx.x;
    int c = t % 12, y = t / 12;
    int b = blockIdx.x;
    if (b < 2 * G) {
        const int2* fh = (b < G) ? fhL : fhH;
        int foff = (b < G) ? 0 : 12;
        int bb = (b < G) ? b : b - G;
        int n0 = bb * 32;
        int nend = min(n0 + 32, N);
        int beg0 = rowptr[n0];
        int span = rowptr[nend] - beg0;
        bool staged = (span <= COL_CAP);
        if (staged) {
            for (int i = t; i < span; i += 384) colS[i] = col[beg0 + i];
            __syncthreads();
        }
        int n = n0 + y;
        if (n < N && n != HUB) {
            int beg = rowptr[n], end = rowptr[n + 1];
            float4 a = staged ? agg12_lds(fh, colS, beg - beg0, end - beg0, c)
                              : agg12_glb(fh, col, beg, end, c);
            float dn = dinv[n];
            out16[(long)n * 24 + foff + c] =
                pack4(a.x * dn, a.y * dn, a.z * dn, a.w * dn);
        }
    } else {
        int hb = b - 2 * G;
        const int2* fh = (hb < 64) ? fhL : fhH;
        int foff = (hb < 64) ? 0 : 12;
        int bb = (hb < 64) ? hb : hb - 64;
        int beg = rowptr[HUB], end = rowptr[HUB + 1];
        int deg = end - beg;
        int chunk = (deg + 2047) / 2048;
        int sid = bb * 32 + y;
        int e = beg + sid * chunk;
        int e1 = min(e + chunk, end);
        float ax = 0.f, ay = 0.f, az = 0.f, aw = 0.f;
        for (; e + 4 <= e1; e += 4) {
            int s0 = col[e + 0], s1 = col[e + 1], s2 = col[e + 2], s3 = col[e + 3];
            int2 r0 = fh[(long)s0 * 12 + c], r1 = fh[(long)s1 * 12 + c];
            int2 r2 = fh[(long)s2 * 12 + c], r3 = fh[(long)s3 * 12 + c];
            float2 l0 = unpack2(r0.x), h0 = unpack2(r0.y);
            float2 l1 = unpack2(r1.x), h1_ = unpack2(r1.y);
            float2 l2 = unpack2(r2.x), h2 = unpack2(r2.y);
            float2 l3 = unpack2(r3.x), h3 = unpack2(r3.y);
            ax += (l0.x + l1.x) + (l2.x + l3.x);
            ay += (l0.y + l1.y) + (l2.y + l3.y);
            az += (h0.x + h1_.x) + (h2.x + h3.x);
            aw += (h0.y + h1_.y) + (h2.y + h3.y);
        }
        for (; e < e1; e++) {
            int s = col[e];
            int2 r = fh[(long)s * 12 + c];
            float2 lo = unpack2(r.x), hi = unpack2(r.y);
            ax += lo.x; ay += lo.y; az += hi.x; aw += hi.y;
        }
        red[y][c] = make_float4(ax, ay, az, aw);
        __syncthreads();
        if (y == 0) {
            float4 tt = red[0][c];
            #pragma unroll
            for (int k = 1; k < 32; k++) {
                float4 u = red[k][c];
                tt.x += u.x; tt.y += u.y; tt.z += u.z; tt.w += u.w;
            }
            float dh = dinv[HUB];
            float* o = hubdest + (foff + c) * 4;
            unsafeAtomicAdd(o + 0, tt.x * dh);
            unsafeAtomicAdd(o + 1, tt.y * dh);
            unsafeAtomicAdd(o + 2, tt.z * dh);
            unsafeAtomicAdd(o + 3, tt.w * dh);
        }
    }
}

// ---------------------------------------------------------------------------
// gemm96_h — h1 halves = fp16(dinv*relu(A@W1+b1)). Unchanged from round 5.
// ---------------------------------------------------------------------------
__global__ __launch_bounds__(192)
void gemm96_h(const float* __restrict__ A, const float* __restrict__ W,
              const float* __restrict__ bias, const float* __restrict__ dinv,
              int2* __restrict__ outL, int2* __restrict__ outH, int N) {
    __shared__ __half Wl[FD * FD];       // 18432 B
    __shared__ float As[64 * 100];       // 25600 B
    int t = threadIdx.y * 24 + threadIdx.x;
    {   // stage W fp32 -> fp16
        const float4* W4 = (const float4*)W;
        #pragma unroll 4
        for (int i = t; i < FD * 24; i += 192) {
            float4 w = W4[i];
            *(int2*)&Wl[i * 4] = pack4(w.x, w.y, w.z, w.w);
        }
    }
    int row0 = blockIdx.x * 64;
    int nrows = min(64, N - row0);
    {
        const float4* A4 = (const float4*)(A + (long)row0 * FD);
        for (int i = t; i < nrows * 24; i += 192) {
            int r = i / 24, g = i % 24;
            *(float4*)&As[r * 100 + g * 4] = A4[i];
        }
    }
    __syncthreads();
    int c = threadIdx.x, y = threadIdx.y;
    float acc[8][4];
    #pragma unroll
    for (int j = 0; j < 8; j++)
        #pragma unroll
        for (int i = 0; i < 4; i++) acc[j][i] = 0.f;
    for (int kk = 0; kk < FD; kk += 4) {
        float4 w0 = lds_w4(Wl, kk + 0, 4 * c);
        float4 w1 = lds_w4(Wl, kk + 1, 4 * c);
        float4 w2 = lds_w4(Wl, kk + 2, 4 * c);
        float4 w3 = lds_w4(Wl, kk + 3, 4 * c);
        #pragma unroll
        for (int j = 0; j < 8; j++) {
            float4 a = *(const float4*)&As[(y + 8 * j) * 100 + kk];
            acc[j][0] = fmaf(a.x, w0.x, fmaf(a.y, w1.x, fmaf(a.z, w2.x, fmaf(a.w, w3.x, acc[j][0]))));
            acc[j][1] = fmaf(a.x, w0.y, fmaf(a.y, w1.y, fmaf(a.z, w2.y, fmaf(a.w, w3.y, acc[j][1]))));
            acc[j][2] = fmaf(a.x, w0.z, fmaf(a.y, w1.z, fmaf(a.z, w2.z, fmaf(a.w, w3.z, acc[j][2]))));
            acc[j][3] = fmaf(a.x, w0.w, fmaf(a.y, w1.w, fmaf(a.z, w2.w, fmaf(a.w, w3.w, acc[j][3]))));
        }
    }
    float4 b4 = *(const float4*)&bias[4 * c];
    #pragma unroll
    for (int j = 0; j < 8; j++) {
        int r = y + 8 * j;
        if (r < nrows) {
            float vx = fmaxf(acc[j][0] + b4.x, 0.f);
            float vy = fmaxf(acc[j][1] + b4.y, 0.f);
            float vz = fmaxf(acc[j][2] + b4.z, 0.f);
            float vw = fmaxf(acc[j][3] + b4.w, 0.f);
            float dr = dinv[row0 + r];
            int2 v = pack4(vx * dr, vy * dr, vz * dr, vw * dr);
            long n = row0 + r;
            if (c < 12) outL[n * 12 + c] = v;
            else        outH[n * 12 + c - 12] = v;
        }
    }
}

// ---------------------------------------------------------------------------
// mfma_dual — mu = A@Wa+ba, ls = A@Wb+bb via v_mfma_f32_16x16x32_f16.
// Unchanged from round 5.
// ---------------------------------------------------------------------------
__global__ __launch_bounds__(256)
void mfma_dual(const __half* __restrict__ a1h, const float* __restrict__ hubacc,
               const __half* __restrict__ Wta, const __half* __restrict__ Wtb,
               const float* __restrict__ ba, const float* __restrict__ bb,
               float* __restrict__ mu, float* __restrict__ ls, int N, int HUB) {
    __shared__ __half WtaL[FD * FD];     // 18432 B
    __shared__ __half WtbL[FD * FD];     // 18432 B
    int t = threadIdx.x;
    {
        const int4* sa = (const int4*)Wta;
        const int4* sb = (const int4*)Wtb;
        int4* da = (int4*)WtaL;
        int4* db = (int4*)WtbL;
        #pragma unroll
        for (int i = t; i < FD * FD / 8; i += 256) { da[i] = sa[i]; db[i] = sb[i]; }
    }
    __syncthreads();
    int wv = t >> 6, lane = t & 63;
    int m = lane & 15, q = lane >> 4;
    long row0 = (long)blockIdx.x * 64 + wv * 16;

    const f16x8* arow = (const f16x8*)&a1h[(row0 + m) * FD + q * 8];
    f16x8 A0 = arow[0];
    f16x8 A1 = arow[4];
    f16x8 A2 = arow[8];
    if (row0 + m == HUB) {   // hub row: a1h[HUB] never written; build from fp32
        A0 = pack8h(hubacc + q * 8);
        A1 = pack8h(hubacc + 32 + q * 8);
        A2 = pack8h(hubacc + 64 + q * 8);
    }

    #pragma unroll
    for (int nt = 0; nt < 6; nt++) {
        int n0 = nt * 16;
        const f16x8* brA = (const f16x8*)&WtaL[(n0 + m) * FD + q * 8];
        const f16x8* brB = (const f16x8*)&WtbL[(n0 + m) * FD + q * 8];
        f32x4 acca = {0.f, 0.f, 0.f, 0.f};
        f32x4 accb = {0.f, 0.f, 0.f, 0.f};
        acca = __builtin_amdgcn_mfma_f32_16x16x32_f16(A0, brA[0], acca, 0, 0, 0);
        acca = __builtin_amdgcn_mfma_f32_16x16x32_f16(A1, brA[4], acca, 0, 0, 0);
        acca = __builtin_amdgcn_mfma_f32_16x16x32_f16(A2, brA[8], acca, 0, 0, 0);
        accb = __builtin_amdgcn_mfma_f32_16x16x32_f16(A0, brB[0], accb, 0, 0, 0);
        accb = __builtin_amdgcn_mfma_f32_16x16x32_f16(A1, brB[4], accb, 0, 0, 0);
        accb = __builtin_amdgcn_mfma_f32_16x16x32_f16(A2, brB[8], accb, 0, 0, 0);
        float bva = ba[n0 + m];
        float bvb = bb[n0 + m];
        #pragma unroll
        for (int r = 0; r < 4; r++) {
            long row = row0 + q * 4 + r;
            if (row < N) {
                mu[row * FD + n0 + m] = acca[r] + bva;
                ls[row * FD + n0 + m] = accb[r] + bvb;
            }
        }
    }
}

// ---------------------------------------------------------------------------
// Launch. 5 dispatches (was 9): build_coop (cooperative; replaces memset,
// deg, scan, prep), pull_hub32, gemm96_h, pull_hub16, mfma_dual.
//   xhL|xhH  = fp16(dinv*x) halves   -> mu slot, lower 9.6 MB
//   a0       = agg(xh)               -> ls slot (fp32; hub row zeroed by P0)
//   h1L|h1H  = fp16 layer-1 halves   -> mu slot, upper 9.6 MB  (a0 dead)
//   a1h      = fp16 agg(h1) full-row -> ws (hub row via hubacc in mfma_dual)
//   mu,ls    = MFMA dual-gemm(a1h)   -> d_out (xh,h1,a0 all dead)
// ws: [counts N][hubacc 96][perm E][rowptr N+1][col E][dinv N]
//     [Wta][Wtb][a1h (N+64)x96 h]  ~= 17.5 MB
// ---------------------------------------------------------------------------
extern "C" void kernel_launch(void* const* d_in, const int* in_sizes, int n_in,
                              void* d_out, int out_size, void* d_ws, size_t ws_size,
                              hipStream_t stream) {
    const float* x   = (const float*)d_in[0];
    const float* W1  = (const float*)d_in[1];
    const float* b1  = (const float*)d_in[2];
    const float* W2a = (const float*)d_in[3];
    const float* b2a = (const float*)d_in[4];
    const float* W2b = (const float*)d_in[5];
    const float* b2b = (const float*)d_in[6];
    const int*   ei  = (const int*)d_in[7];

    const int N   = in_sizes[0] / FD;
    const int E   = in_sizes[7] / 2;
    const int HUB = N - 1;
    const int* src = ei;
    const int* dst = ei + E;

    int* counts   = (int*)d_ws;                 // N
    float* hubacc = (float*)(counts + N);       // 96
    int* perm     = (int*)(hubacc + FD);        // E
    int* rowptr   = perm + E;                   // N+1
    int* col      = rowptr + (N + 1);           // E
    float* dinv   = (float*)(col + E);          // N
    uintptr_t p = (uintptr_t)(dinv + N);
    p = (p + 15) & ~(uintptr_t)15;
    __half* Wta = (__half*)p;                   // FD*FD
    __half* Wtb = Wta + FD * FD;                // FD*FD
    __half* a1h = Wtb + FD * FD;                // (N+64)*FD halves, 16B-aligned

    float* mu_slot = (float*)d_out;
    float* ls_slot = (float*)d_out + (size_t)N * FD;
    int2* xhL = (int2*)mu_slot;                      // 4.8 MB
    int2* xhH = xhL + (size_t)N * 12;                // 4.8 MB
    int2* h1L = (int2*)mu_slot + (size_t)N * 24;     // 4.8 MB
    int2* h1H = h1L + (size_t)N * 12;                // 4.8 MB
    float* a0 = ls_slot;
    float* a0hub = a0 + (size_t)HUB * FD;

    // cooperative CSR build + convert (replaces memset/deg/scan/prep)
    {
        int E_ = E, N_ = N, HUB_ = HUB;
        const int* src_ = src;
        const int* dst_ = dst;
        const float* x_ = x;
        const float* W2a_ = W2a;
        const float* W2b_ = W2b;
        void* bargs[] = {
            (void*)&src_, (void*)&dst_, (void*)&E_, (void*)&x_,
            (void*)&N_, (void*)&HUB_, (void*)&W2a_, (void*)&W2b_,
            (void*)&counts, (void*)&perm, (void*)&rowptr, (void*)&dinv,
            (void*)&col, (void*)&xhL, (void*)&xhH,
            (void*)&Wta, (void*)&Wtb, (void*)&hubacc, (void*)&a0hub
        };
        (void)hipLaunchCooperativeKernel((const void*)build_coop,
                                         dim3(256), dim3(1024),
                                         bargs, 0, stream);
    }

    int G = (N + 31) / 32;
    int gemmG = (N + 63) / 64;
    dim3 gemmB(24, 8);

    // layer 1 (half-table pulls + hub merged; hub accumulates into a0 hub row)
    pull_hub32<<<dim3(2 * G + 128), dim3(384), 0, stream>>>(
        xhL, xhH, dinv, rowptr, col, N, HUB, G, a0, a0hub);
    gemm96_h  <<<dim3(gemmG), gemmB, 0, stream>>>(a0, W1, b1, dinv, h1L, h1H, N);

    // layer 2 (half-table pulls + hub merged; hub row via hubacc in mfma)
    pull_hub16<<<dim3(2 * G + 128), dim3(384), 0, stream>>>(
        h1L, h1H, dinv, rowptr, col, N, HUB, G, (int2*)a1h, hubacc);
    mfma_dual <<<dim3(gemmG), dim3(256), 0, stream>>>(a1h, hubacc, Wta, Wtb,
                                                      b2a, b2b, mu_slot, ls_slot,
                                                      N, HUB);
}

// Round 7
// 262.094 us; speedup vs baseline: 2.0795x; 2.0795x over previous
//
#include <hip/hip_runtime.h>
#include <hip/hip_fp16.h>

#define FD 96        // feature dim
#define COL_CAP 2048 // LDS col staging capacity (32 rows, avg ~18 edges; only
                     // the block containing HUB (~50K edges) overflows)

typedef _Float16 f16x8 __attribute__((ext_vector_type(8)));
typedef float f32x4 __attribute__((ext_vector_type(4)));

// ---- fp16 pack/unpack helpers ---------------------------------------------
__device__ inline float2 unpack2(int v) {
    __half2 h = *reinterpret_cast<__half2*>(&v);
    return __half22float2(h);
}
__device__ inline int2 pack4(float a, float b, float c, float d) {
    __half2 lo = __floats2half2_rn(a, b);
    __half2 hi = __floats2half2_rn(c, d);
    int2 r;
    r.x = *reinterpret_cast<int*>(&lo);
    r.y = *reinterpret_cast<int*>(&hi);
    return r;
}
// pack 8 fp32 -> f16x8 with pack4 rounding
__device__ inline f16x8 pack8h(const float* __restrict__ h) {
    int2 a = pack4(h[0], h[1], h[2], h[3]);
    int2 b = pack4(h[4], h[5], h[6], h[7]);
    int4 r = make_int4(a.x, a.y, b.x, b.y);
    return *reinterpret_cast<f16x8*>(&r);
}
// load 4 fp16 (int2) from LDS -> float4
__device__ inline float4 lds_w4(const __half* Wl, int k, int c4) {
    int2 wv = *(const int2*)&Wl[k * FD + c4];
    float2 lo = unpack2(wv.x), hi = unpack2(wv.y);
    return make_float4(lo.x, lo.y, hi.x, hi.y);
}

// ---- prefetch-pipelined aggregation over a HALF-TABLE ---------------------
// fb = byte base of half-table (rows of 96 B). colS holds PRE-SCALED byte
// offsets (s*96). Issues chunk k+1's 8 loads before accumulating chunk k
// (16 outstanding loads/thread). Accumulation order identical to the
// verified round-0/4/5 kernels -> bit-identical results.
__device__ inline float4 agg12_pf(const char* __restrict__ fb,
                                  const int* colS, int beg, int end, int c) {
    float ax = 0.f, ay = 0.f, az = 0.f, aw = 0.f;
    const int cb = c * 8;
    int e = beg;
    int2 cur[8], nxt[8];
    bool have = (e + 8 <= end);
    if (have) {
        #pragma unroll
        for (int k = 0; k < 8; k++)
            cur[k] = *(const int2*)(fb + colS[e + k] + cb);
    }
    while (have) {
        int en = e + 8;
        bool haven = (en + 8 <= end);
        if (haven) {
            #pragma unroll
            for (int k = 0; k < 8; k++)
                nxt[k] = *(const int2*)(fb + colS[en + k] + cb);
        }
        float2 l0 = unpack2(cur[0].x), h0 = unpack2(cur[0].y);
        float2 l1 = unpack2(cur[1].x), h1_ = unpack2(cur[1].y);
        float2 l2 = unpack2(cur[2].x), h2 = unpack2(cur[2].y);
        float2 l3 = unpack2(cur[3].x), h3 = unpack2(cur[3].y);
        float2 l4 = unpack2(cur[4].x), h4 = unpack2(cur[4].y);
        float2 l5 = unpack2(cur[5].x), h5 = unpack2(cur[5].y);
        float2 l6 = unpack2(cur[6].x), h6 = unpack2(cur[6].y);
        float2 l7 = unpack2(cur[7].x), h7 = unpack2(cur[7].y);
        ax += (l0.x + l1.x) + (l2.x + l3.x) + (l4.x + l5.x) + (l6.x + l7.x);
        ay += (l0.y + l1.y) + (l2.y + l3.y) + (l4.y + l5.y) + (l6.y + l7.y);
        az += (h0.x + h1_.x) + (h2.x + h3.x) + (h4.x + h5.x) + (h6.x + h7.x);
        aw += (h0.y + h1_.y) + (h2.y + h3.y) + (h4.y + h5.y) + (h6.y + h7.y);
        if (haven) {
            #pragma unroll
            for (int k = 0; k < 8; k++) cur[k] = nxt[k];
        }
        e = en; have = haven;
    }
    for (; e < end; e++) {
        int2 r = *(const int2*)(fb + colS[e] + cb);
        float2 lo = unpack2(r.x), hi = unpack2(r.y);
        ax += lo.x; ay += lo.y; az += hi.x; aw += hi.y;
    }
    return make_float4(ax, ay, az, aw);
}

// ---- global-col fallback (only the block whose span contains HUB) ---------
__device__ inline float4 agg12_glb(const int2* __restrict__ fh,
                                   const int* __restrict__ col,
                                   int beg, int end, int c) {
    float ax = 0.f, ay = 0.f, az = 0.f, aw = 0.f;
    int e = beg;
    for (; e + 8 <= end; e += 8) {
        int s0 = col[e + 0], s1 = col[e + 1], s2 = col[e + 2], s3 = col[e + 3];
        int s4 = col[e + 4], s5 = col[e + 5], s6 = col[e + 6], s7 = col[e + 7];
        int2 r0 = fh[(long)s0 * 12 + c], r1 = fh[(long)s1 * 12 + c];
        int2 r2 = fh[(long)s2 * 12 + c], r3 = fh[(long)s3 * 12 + c];
        int2 r4 = fh[(long)s4 * 12 + c], r5 = fh[(long)s5 * 12 + c];
        int2 r6 = fh[(long)s6 * 12 + c], r7 = fh[(long)s7 * 12 + c];
        float2 l0 = unpack2(r0.x), h0 = unpack2(r0.y);
        float2 l1 = unpack2(r1.x), h1_ = unpack2(r1.y);
        float2 l2 = unpack2(r2.x), h2 = unpack2(r2.y);
        float2 l3 = unpack2(r3.x), h3 = unpack2(r3.y);
        float2 l4 = unpack2(r4.x), h4 = unpack2(r4.y);
        float2 l5 = unpack2(r5.x), h5 = unpack2(r5.y);
        float2 l6 = unpack2(r6.x), h6 = unpack2(r6.y);
        float2 l7 = unpack2(r7.x), h7 = unpack2(r7.y);
        ax += (l0.x + l1.x) + (l2.x + l3.x) + (l4.x + l5.x) + (l6.x + l7.x);
        ay += (l0.y + l1.y) + (l2.y + l3.y) + (l4.y + l5.y) + (l6.y + l7.y);
        az += (h0.x + h1_.x) + (h2.x + h3.x) + (h4.x + h5.x) + (h6.x + h7.x);
        aw += (h0.y + h1_.y) + (h2.y + h3.y) + (h4.y + h5.y) + (h6.y + h7.y);
    }
    for (; e < end; e++) {
        int s = col[e];
        int2 r = fh[(long)s * 12 + c];
        float2 lo = unpack2(r.x), hi = unpack2(r.y);
        ax += lo.x; ay += lo.y; az += hi.x; aw += hi.y;
    }
    return make_float4(ax, ay, az, aw);
}

// ---------------------------------------------------------------------------
// K1: degree histogram + per-edge rank capture (perm). Hub via ballot.
// ---------------------------------------------------------------------------
__global__ void deg_kernel(const int* __restrict__ dst, int E, int HUB,
                           int* __restrict__ counts, int* __restrict__ perm) {
    int e = blockIdx.x * 256 + threadIdx.x;
    int d = (e < E) ? dst[e] : -1;
    bool isHub = (d == HUB);
    unsigned long long m = __ballot(isHub);
    if (isHub) {
        int lane = threadIdx.x & 63;
        int leader = __ffsll((unsigned long long)m) - 1;
        int base = 0;
        if (lane == leader) base = atomicAdd(&counts[HUB], (int)__popcll(m));
        base = __shfl(base, leader);
        unsigned long long below = m & ((1ull << lane) - 1ull);
        perm[e] = base + (int)__popcll(below);
    } else if (d >= 0) {
        perm[e] = atomicAdd(&counts[d], 1);
    }
}

// ---------------------------------------------------------------------------
// K2: single-kernel scan. Block b brute-force sums counts[0..b*1024), then
// scans its own 1024-chunk. Emits rowptr[0..N] and dinv (fused).
// ---------------------------------------------------------------------------
__global__ __launch_bounds__(1024)
void scan_kernel(const int* __restrict__ counts, int N,
                 int* __restrict__ rowptr, float* __restrict__ dinv) {
    int t = threadIdx.x, lane = t & 63, wv = t >> 6;
    int base = blockIdx.x * 1024;
    int pre = 0;
    for (int idx = t; idx < base; idx += 1024) pre += counts[idx];
    #pragma unroll
    for (int off = 32; off; off >>= 1) pre += __shfl_down(pre, off);
    __shared__ int wsA[16];
    __shared__ int preS;
    if (lane == 0) wsA[wv] = pre;
    __syncthreads();
    if (t == 0) {
        int s = 0;
        #pragma unroll
        for (int k = 0; k < 16; k++) s += wsA[k];
        preS = s;
    }
    __syncthreads();
    int blockpre = preS;
    int i = base + t;
    int v = (i < N) ? counts[i] : 0;
    int x = v;
    #pragma unroll
    for (int off = 1; off < 64; off <<= 1) {
        int u = __shfl_up(x, off);
        if (lane >= off) x += u;
    }
    __shared__ int wsum[16];
    if (lane == 63) wsum[wv] = x;
    __syncthreads();
    if (wv == 0 && lane < 16) {
        int w = wsum[lane];
        #pragma unroll
        for (int off = 1; off < 16; off <<= 1) {
            int u = __shfl_up(w, off);
            if (lane >= off) w += u;
        }
        wsum[lane] = w;
    }
    __syncthreads();
    int waveoff = (wv == 0) ? 0 : wsum[wv - 1];
    if (i <= N) rowptr[i] = blockpre + waveoff + x - v;
    if (i < N) {
        float d = (float)v;
        dinv[i] = (d > 0.f) ? rsqrtf(fmaxf(d, 1.f)) : 0.f;
    }
}

// ---------------------------------------------------------------------------
// K3: prep — fused {CSR col fill} + {xh halves = fp16(dinv*x)} + {Wt convert}
// + {zero a0 hub row}.
// ---------------------------------------------------------------------------
__global__ __launch_bounds__(256)
void prep_kernel(const int* __restrict__ src, const int* __restrict__ dst,
                 const int* __restrict__ perm, const int* __restrict__ rowptr,
                 int E,
                 const float* __restrict__ x, const float* __restrict__ dinv,
                 int N,
                 const float* __restrict__ W2a, const float* __restrict__ W2b,
                 int* __restrict__ col,
                 int2* __restrict__ xhL, int2* __restrict__ xhH,
                 __half* __restrict__ Wta, __half* __restrict__ Wtb,
                 float* __restrict__ a0hub, int gfill, int gconv, int gwt) {
    int b = blockIdx.x;
    if (b < gfill) {
        int e = b * 256 + threadIdx.x;
        if (e >= E) return;
        int d = dst[e];
        col[rowptr[d] + perm[e]] = src[e];
    } else if (b < gfill + gconv) {
        int i = (b - gfill) * 256 + threadIdx.x;
        if (i >= N * 24) return;
        int n = i / 24, g = i % 24;
        float dn = dinv[n];
        float4 a = ((const float4*)x)[i];
        int2 v = pack4(a.x * dn, a.y * dn, a.z * dn, a.w * dn);
        if (g < 12) xhL[(long)n * 12 + g] = v;
        else        xhH[(long)n * 12 + g - 12] = v;
    } else if (b < gfill + gconv + gwt) {
        int i = (b - gfill - gconv) * 256 + threadIdx.x;
        if (i >= FD * FD) return;
        int n = i / FD, k = i % FD;
        Wta[i] = __float2half(W2a[k * FD + n]);
        Wtb[i] = __float2half(W2b[k * FD + n]);
    } else {
        int i = threadIdx.x;
        if (i < FD) a0hub[i] = 0.f;
    }
}

// ---------------------------------------------------------------------------
// Merged half-table pull+hub kernels. Grid = 2*G + 128; block 384 = (c 0..11,
// y 0..31). colS holds PRE-SCALED byte offsets (col*96) for the pipelined
// gather; the rare unstaged block (hub span) falls back to raw col.
// ---------------------------------------------------------------------------
__global__ __launch_bounds__(384)
void pull_hub32(const int2* __restrict__ fhL, const int2* __restrict__ fhH,
                const float* __restrict__ dinv,
                const int* __restrict__ rowptr, const int* __restrict__ col,
                int N, int HUB, int G,
                float* __restrict__ out, float* __restrict__ hubdest) {
    __shared__ int colS[COL_CAP];
    __shared__ float4 red[32][12];
    int t = threadIdx.x;
    int c = t % 12, y = t / 12;
    int b = blockIdx.x;
    if (b < 2 * G) {
        const int2* fh = (b < G) ? fhL : fhH;
        int foff = (b < G) ? 0 : 12;
        int bb = (b < G) ? b : b - G;
        int n0 = bb * 32;
        int nend = min(n0 + 32, N);
        int beg0 = rowptr[n0];
        int span = rowptr[nend] - beg0;
        bool staged = (span <= COL_CAP);
        if (staged) {
            for (int i = t; i < span; i += 384) colS[i] = col[beg0 + i] * 96;
            __syncthreads();
        }
        int n = n0 + y;
        if (n < N && n != HUB) {
            int beg = rowptr[n], end = rowptr[n + 1];
            float4 a = staged
                ? agg12_pf((const char*)fh, colS, beg - beg0, end - beg0, c)
                : agg12_glb(fh, col, beg, end, c);
            float dn = dinv[n];
            ((float4*)out)[(long)n * 24 + foff + c] =
                make_float4(a.x * dn, a.y * dn, a.z * dn, a.w * dn);
        }
    } else {
        int hb = b - 2 * G;
        const int2* fh = (hb < 64) ? fhL : fhH;
        int foff = (hb < 64) ? 0 : 12;
        int bb = (hb < 64) ? hb : hb - 64;
        int beg = rowptr[HUB], end = rowptr[HUB + 1];
        int deg = end - beg;
        int chunk = (deg + 2047) / 2048;
        int sid = bb * 32 + y;
        int e = beg + sid * chunk;
        int e1 = min(e + chunk, end);
        float ax = 0.f, ay = 0.f, az = 0.f, aw = 0.f;
        for (; e + 4 <= e1; e += 4) {
            int s0 = col[e + 0], s1 = col[e + 1], s2 = col[e + 2], s3 = col[e + 3];
            int2 r0 = fh[(long)s0 * 12 + c], r1 = fh[(long)s1 * 12 + c];
            int2 r2 = fh[(long)s2 * 12 + c], r3 = fh[(long)s3 * 12 + c];
            float2 l0 = unpack2(r0.x), h0 = unpack2(r0.y);
            float2 l1 = unpack2(r1.x), h1_ = unpack2(r1.y);
            float2 l2 = unpack2(r2.x), h2 = unpack2(r2.y);
            float2 l3 = unpack2(r3.x), h3 = unpack2(r3.y);
            ax += (l0.x + l1.x) + (l2.x + l3.x);
            ay += (l0.y + l1.y) + (l2.y + l3.y);
            az += (h0.x + h1_.x) + (h2.x + h3.x);
            aw += (h0.y + h1_.y) + (h2.y + h3.y);
        }
        for (; e < e1; e++) {
            int s = col[e];
            int2 r = fh[(long)s * 12 + c];
            float2 lo = unpack2(r.x), hi = unpack2(r.y);
            ax += lo.x; ay += lo.y; az += hi.x; aw += hi.y;
        }
        red[y][c] = make_float4(ax, ay, az, aw);
        __syncthreads();
        if (y == 0) {
            float4 tt = red[0][c];
            #pragma unroll
            for (int k = 1; k < 32; k++) {
                float4 u = red[k][c];
                tt.x += u.x; tt.y += u.y; tt.z += u.z; tt.w += u.w;
            }
            float dh = dinv[HUB];
            float* o = hubdest + (foff + c) * 4;
            unsafeAtomicAdd(o + 0, tt.x * dh);
            unsafeAtomicAdd(o + 1, tt.y * dh);
            unsafeAtomicAdd(o + 2, tt.z * dh);
            unsafeAtomicAdd(o + 3, tt.w * dh);
        }
    }
}

__global__ __launch_bounds__(384)
void pull_hub16(const int2* __restrict__ fhL, const int2* __restrict__ fhH,
                const float* __restrict__ dinv,
                const int* __restrict__ rowptr, const int* __restrict__ col,
                int N, int HUB, int G,
                int2* __restrict__ out16, float* __restrict__ hubdest) {
    __shared__ int colS[COL_CAP];
    __shared__ float4 red[32][12];
    int t = threadIdx.x;
    int c = t % 12, y = t / 12;
    int b = blockIdx.x;
    if (b < 2 * G) {
        const int2* fh = (b < G) ? fhL : fhH;
        int foff = (b < G) ? 0 : 12;
        int bb = (b < G) ? b : b - G;
        int n0 = bb * 32;
        int nend = min(n0 + 32, N);
        int beg0 = rowptr[n0];
        int span = rowptr[nend] - beg0;
        bool staged = (span <= COL_CAP);
        if (staged) {
            for (int i = t; i < span; i += 384) colS[i] = col[beg0 + i] * 96;
            __syncthreads();
        }
        int n = n0 + y;
        if (n < N && n != HUB) {
            int beg = rowptr[n], end = rowptr[n + 1];
            float4 a = staged
                ? agg12_pf((const char*)fh, colS, beg - beg0, end - beg0, c)
                : agg12_glb(fh, col, beg, end, c);
            float dn = dinv[n];
            out16[(long)n * 24 + foff + c] =
                pack4(a.x * dn, a.y * dn, a.z * dn, a.w * dn);
        }
    } else {
        int hb = b - 2 * G;
        const int2* fh = (hb < 64) ? fhL : fhH;
        int foff = (hb < 64) ? 0 : 12;
        int bb = (hb < 64) ? hb : hb - 64;
        int beg = rowptr[HUB], end = rowptr[HUB + 1];
        int deg = end - beg;
        int chunk = (deg + 2047) / 2048;
        int sid = bb * 32 + y;
        int e = beg + sid * chunk;
        int e1 = min(e + chunk, end);
        float ax = 0.f, ay = 0.f, az = 0.f, aw = 0.f;
        for (; e + 4 <= e1; e += 4) {
            int s0 = col[e + 0], s1 = col[e + 1], s2 = col[e + 2], s3 = col[e + 3];
            int2 r0 = fh[(long)s0 * 12 + c], r1 = fh[(long)s1 * 12 + c];
            int2 r2 = fh[(long)s2 * 12 + c], r3 = fh[(long)s3 * 12 + c];
            float2 l0 = unpack2(r0.x), h0 = unpack2(r0.y);
            float2 l1 = unpack2(r1.x), h1_ = unpack2(r1.y);
            float2 l2 = unpack2(r2.x), h2 = unpack2(r2.y);
            float2 l3 = unpack2(r3.x), h3 = unpack2(r3.y);
            ax += (l0.x + l1.x) + (l2.x + l3.x);
            ay += (l0.y + l1.y) + (l2.y + l3.y);
            az += (h0.x + h1_.x) + (h2.x + h3.x);
            aw += (h0.y + h1_.y) + (h2.y + h3.y);
        }
        for (; e < e1; e++) {
            int s = col[e];
            int2 r = fh[(long)s * 12 + c];
            float2 lo = unpack2(r.x), hi = unpack2(r.y);
            ax += lo.x; ay += lo.y; az += hi.x; aw += hi.y;
        }
        red[y][c] = make_float4(ax, ay, az, aw);
        __syncthreads();
        if (y == 0) {
            float4 tt = red[0][c];
            #pragma unroll
            for (int k = 1; k < 32; k++) {
                float4 u = red[k][c];
                tt.x += u.x; tt.y += u.y; tt.z += u.z; tt.w += u.w;
            }
            float dh = dinv[HUB];
            float* o = hubdest + (foff + c) * 4;
            unsafeAtomicAdd(o + 0, tt.x * dh);
            unsafeAtomicAdd(o + 1, tt.y * dh);
            unsafeAtomicAdd(o + 2, tt.z * dh);
            unsafeAtomicAdd(o + 3, tt.w * dh);
        }
    }
}

// ---------------------------------------------------------------------------
// gemm96_h — h1 halves = fp16(dinv*relu(A@W1+b1)). Unchanged (verified).
// ---------------------------------------------------------------------------
__global__ __launch_bounds__(192)
void gemm96_h(const float* __restrict__ A, const float* __restrict__ W,
              const float* __restrict__ bias, const float* __restrict__ dinv,
              int2* __restrict__ outL, int2* __restrict__ outH, int N) {
    __shared__ __half Wl[FD * FD];       // 18432 B
    __shared__ float As[64 * 100];       // 25600 B
    int t = threadIdx.y * 24 + threadIdx.x;
    {   // stage W fp32 -> fp16
        const float4* W4 = (const float4*)W;
        #pragma unroll 4
        for (int i = t; i < FD * 24; i += 192) {
            float4 w = W4[i];
            *(int2*)&Wl[i * 4] = pack4(w.x, w.y, w.z, w.w);
        }
    }
    int row0 = blockIdx.x * 64;
    int nrows = min(64, N - row0);
    {
        const float4* A4 = (const float4*)(A + (long)row0 * FD);
        for (int i = t; i < nrows * 24; i += 192) {
            int r = i / 24, g = i % 24;
            *(float4*)&As[r * 100 + g * 4] = A4[i];
        }
    }
    __syncthreads();
    int c = threadIdx.x, y = threadIdx.y;
    float acc[8][4];
    #pragma unroll
    for (int j = 0; j < 8; j++)
        #pragma unroll
        for (int i = 0; i < 4; i++) acc[j][i] = 0.f;
    for (int kk = 0; kk < FD; kk += 4) {
        float4 w0 = lds_w4(Wl, kk + 0, 4 * c);
        float4 w1 = lds_w4(Wl, kk + 1, 4 * c);
        float4 w2 = lds_w4(Wl, kk + 2, 4 * c);
        float4 w3 = lds_w4(Wl, kk + 3, 4 * c);
        #pragma unroll
        for (int j = 0; j < 8; j++) {
            float4 a = *(const float4*)&As[(y + 8 * j) * 100 + kk];
            acc[j][0] = fmaf(a.x, w0.x, fmaf(a.y, w1.x, fmaf(a.z, w2.x, fmaf(a.w, w3.x, acc[j][0]))));
            acc[j][1] = fmaf(a.x, w0.y, fmaf(a.y, w1.y, fmaf(a.z, w2.y, fmaf(a.w, w3.y, acc[j][1]))));
            acc[j][2] = fmaf(a.x, w0.z, fmaf(a.y, w1.z, fmaf(a.z, w2.z, fmaf(a.w, w3.z, acc[j][2]))));
            acc[j][3] = fmaf(a.x, w0.w, fmaf(a.y, w1.w, fmaf(a.z, w2.w, fmaf(a.w, w3.w, acc[j][3]))));
        }
    }
    float4 b4 = *(const float4*)&bias[4 * c];
    #pragma unroll
    for (int j = 0; j < 8; j++) {
        int r = y + 8 * j;
        if (r < nrows) {
            float vx = fmaxf(acc[j][0] + b4.x, 0.f);
            float vy = fmaxf(acc[j][1] + b4.y, 0.f);
            float vz = fmaxf(acc[j][2] + b4.z, 0.f);
            float vw = fmaxf(acc[j][3] + b4.w, 0.f);
            float dr = dinv[row0 + r];
            int2 v = pack4(vx * dr, vy * dr, vz * dr, vw * dr);
            long n = row0 + r;
            if (c < 12) outL[n * 12 + c] = v;
            else        outH[n * 12 + c - 12] = v;
        }
    }
}

// ---------------------------------------------------------------------------
// mfma_dual — mu = A@Wa+ba, ls = A@Wb+bb via v_mfma_f32_16x16x32_f16.
// Unchanged (verified).
// ---------------------------------------------------------------------------
__global__ __launch_bounds__(256)
void mfma_dual(const __half* __restrict__ a1h, const float* __restrict__ hubacc,
               const __half* __restrict__ Wta, const __half* __restrict__ Wtb,
               const float* __restrict__ ba, const float* __restrict__ bb,
               float* __restrict__ mu, float* __restrict__ ls, int N, int HUB) {
    __shared__ __half WtaL[FD * FD];     // 18432 B
    __shared__ __half WtbL[FD * FD];     // 18432 B
    int t = threadIdx.x;
    {
        const int4* sa = (const int4*)Wta;
        const int4* sb = (const int4*)Wtb;
        int4* da = (int4*)WtaL;
        int4* db = (int4*)WtbL;
        #pragma unroll
        for (int i = t; i < FD * FD / 8; i += 256) { da[i] = sa[i]; db[i] = sb[i]; }
    }
    __syncthreads();
    int wv = t >> 6, lane = t & 63;
    int m = lane & 15, q = lane >> 4;
    long row0 = (long)blockIdx.x * 64 + wv * 16;

    const f16x8* arow = (const f16x8*)&a1h[(row0 + m) * FD + q * 8];
    f16x8 A0 = arow[0];
    f16x8 A1 = arow[4];
    f16x8 A2 = arow[8];
    if (row0 + m == HUB) {   // hub row: a1h[HUB] never written; build from fp32
        A0 = pack8h(hubacc + q * 8);
        A1 = pack8h(hubacc + 32 + q * 8);
        A2 = pack8h(hubacc + 64 + q * 8);
    }

    #pragma unroll
    for (int nt = 0; nt < 6; nt++) {
        int n0 = nt * 16;
        const f16x8* brA = (const f16x8*)&WtaL[(n0 + m) * FD + q * 8];
        const f16x8* brB = (const f16x8*)&WtbL[(n0 + m) * FD + q * 8];
        f32x4 acca = {0.f, 0.f, 0.f, 0.f};
        f32x4 accb = {0.f, 0.f, 0.f, 0.f};
        acca = __builtin_amdgcn_mfma_f32_16x16x32_f16(A0, brA[0], acca, 0, 0, 0);
        acca = __builtin_amdgcn_mfma_f32_16x16x32_f16(A1, brA[4], acca, 0, 0, 0);
        acca = __builtin_amdgcn_mfma_f32_16x16x32_f16(A2, brA[8], acca, 0, 0, 0);
        accb = __builtin_amdgcn_mfma_f32_16x16x32_f16(A0, brB[0], accb, 0, 0, 0);
        accb = __builtin_amdgcn_mfma_f32_16x16x32_f16(A1, brB[4], accb, 0, 0, 0);
        accb = __builtin_amdgcn_mfma_f32_16x16x32_f16(A2, brB[8], accb, 0, 0, 0);
        float bva = ba[n0 + m];
        float bvb = bb[n0 + m];
        #pragma unroll
        for (int r = 0; r < 4; r++) {
            long row = row0 + q * 4 + r;
            if (row < N) {
                mu[row * FD + n0 + m] = acca[r] + bva;
                ls[row * FD + n0 + m] = accb[r] + bvb;
            }
        }
    }
}

// ---------------------------------------------------------------------------
// Launch. 8 dispatches (round-5 verified structure; coop experiment reverted):
// memset, deg, scan, prep, pull_hub32, gemm96_h, pull_hub16, mfma_dual.
//   xhL|xhH  = fp16(dinv*x) halves   -> mu slot, lower 9.6 MB
//   a0       = agg(xh)               -> ls slot (fp32; hub row zeroed by prep)
//   h1L|h1H  = fp16 layer-1 halves   -> mu slot, upper 9.6 MB  (a0 dead)
//   a1h      = fp16 agg(h1) full-row -> ws (hub row via hubacc in mfma_dual)
//   mu,ls    = MFMA dual-gemm(a1h)   -> d_out (xh,h1,a0 all dead)
// ws: [counts N][hubacc 96][perm E][rowptr N+1][col E][dinv N]
//     [Wta][Wtb][a1h (N+64)x96 h]  ~= 17.5 MB
// ---------------------------------------------------------------------------
extern "C" void kernel_launch(void* const* d_in, const int* in_sizes, int n_in,
                              void* d_out, int out_size, void* d_ws, size_t ws_size,
                              hipStream_t stream) {
    const float* x   = (const float*)d_in[0];
    const float* W1  = (const float*)d_in[1];
    const float* b1  = (const float*)d_in[2];
    const float* W2a = (const float*)d_in[3];
    const float* b2a = (const float*)d_in[4];
    const float* W2b = (const float*)d_in[5];
    const float* b2b = (const float*)d_in[6];
    const int*   ei  = (const int*)d_in[7];

    const int N   = in_sizes[0] / FD;
    const int E   = in_sizes[7] / 2;
    const int HUB = N - 1;
    const int* src = ei;
    const int* dst = ei + E;
    const int NB  = (N + 1023) / 1024;

    int* counts   = (int*)d_ws;                 // N
    float* hubacc = (float*)(counts + N);       // 96
    int* perm     = (int*)(hubacc + FD);        // E
    int* rowptr   = perm + E;                   // N+1
    int* col      = rowptr + (N + 1);           // E
    float* dinv   = (float*)(col + E);          // N
    uintptr_t p = (uintptr_t)(dinv + N);
    p = (p + 15) & ~(uintptr_t)15;
    __half* Wta = (__half*)p;                   // FD*FD
    __half* Wtb = Wta + FD * FD;                // FD*FD
    __half* a1h = Wtb + FD * FD;                // (N+64)*FD halves, 16B-aligned

    float* mu_slot = (float*)d_out;
    float* ls_slot = (float*)d_out + (size_t)N * FD;
    int2* xhL = (int2*)mu_slot;                      // 4.8 MB
    int2* xhH = xhL + (size_t)N * 12;                // 4.8 MB
    int2* h1L = (int2*)mu_slot + (size_t)N * 24;     // 4.8 MB
    int2* h1H = h1L + (size_t)N * 12;                // 4.8 MB
    float* a0 = ls_slot;
    float* a0hub = a0 + (size_t)HUB * FD;

    // zero counts + hubacc (contiguous)
    (void)hipMemsetAsync(counts, 0, ((size_t)N + FD) * sizeof(int), stream);

    deg_kernel <<<dim3((E + 255) / 256), dim3(256), 0, stream>>>(dst, E, HUB,
                                                                 counts, perm);
    scan_kernel<<<dim3(NB), dim3(1024), 0, stream>>>(counts, N, rowptr, dinv);

    int gfill = (E + 255) / 256;
    int gconv = (N * 24 + 255) / 256;
    int gwt   = (FD * FD + 255) / 256;
    prep_kernel<<<dim3(gfill + gconv + gwt + 1), dim3(256), 0, stream>>>(
        src, dst, perm, rowptr, E, x, dinv, N, W2a, W2b,
        col, xhL, xhH, Wta, Wtb, a0hub, gfill, gconv, gwt);

    int G = (N + 31) / 32;
    int gemmG = (N + 63) / 64;
    dim3 gemmB(24, 8);

    // layer 1 (half-table pulls + hub merged; hub accumulates into a0 hub row)
    pull_hub32<<<dim3(2 * G + 128), dim3(384), 0, stream>>>(
        xhL, xhH, dinv, rowptr, col, N, HUB, G, a0, a0hub);
    gemm96_h  <<<dim3(gemmG), gemmB, 0, stream>>>(a0, W1, b1, dinv, h1L, h1H, N);

    // layer 2 (half-table pulls + hub merged; hub row via hubacc in mfma)
    pull_hub16<<<dim3(2 * G + 128), dim3(384), 0, stream>>>(
        h1L, h1H, dinv, rowptr, col, N, HUB, G, (int2*)a1h, hubacc);
    mfma_dual <<<dim3(gemmG), dim3(256), 0, stream>>>(a1h, hubacc, Wta, Wtb,
                                                      b2a, b2b, mu_slot, ls_slot,
                                                      N, HUB);
}

// Round 8
// 254.170 us; speedup vs baseline: 2.1443x; 1.0312x over previous
//
#include <hip/hip_runtime.h>
#include <hip/hip_fp16.h>

#define FD 96        // feature dim
#define QF 24        // features per quarter-table
#define QI 6         // int2 (4-feat) groups per quarter row (48 B)
#define COL_CAP 3072 // LDS col staging capacity (64 rows, avg ~18 edges)

typedef _Float16 f16x8 __attribute__((ext_vector_type(8)));
typedef float f32x4 __attribute__((ext_vector_type(4)));

// ---- fp16 pack/unpack helpers ---------------------------------------------
__device__ inline float2 unpack2(int v) {
    __half2 h = *reinterpret_cast<__half2*>(&v);
    return __half22float2(h);
}
__device__ inline int2 pack4(float a, float b, float c, float d) {
    __half2 lo = __floats2half2_rn(a, b);
    __half2 hi = __floats2half2_rn(c, d);
    int2 r;
    r.x = *reinterpret_cast<int*>(&lo);
    r.y = *reinterpret_cast<int*>(&hi);
    return r;
}
// pack 8 fp32 -> f16x8 with pack4 rounding
__device__ inline f16x8 pack8h(const float* __restrict__ h) {
    int2 a = pack4(h[0], h[1], h[2], h[3]);
    int2 b = pack4(h[4], h[5], h[6], h[7]);
    int4 r = make_int4(a.x, a.y, b.x, b.y);
    return *reinterpret_cast<f16x8*>(&r);
}
// load 4 fp16 (int2) from LDS -> float4
__device__ inline float4 lds_w4(const __half* Wl, int k, int c4) {
    int2 wv = *(const int2*)&Wl[k * FD + c4];
    float2 lo = unpack2(wv.x), hi = unpack2(wv.y);
    return make_float4(lo.x, lo.y, hi.x, hi.y);
}

// ---- 8-unroll aggregation over a QUARTER-TABLE (48 B rows) ----------------
// c6 in 0..5 selects the 4-feature group. Per-feature accumulation chain
// identical to the verified round-0/4/5 kernels (same 8-edge pairwise tree,
// same tail) -> bit-identical results. colS holds PRE-SCALED byte offsets
// (s*48).
__device__ inline float4 agg6_lds(const char* __restrict__ fbq,
                                  const int* colS, int beg, int end, int c6) {
    float ax = 0.f, ay = 0.f, az = 0.f, aw = 0.f;
    const int cb = c6 * 8;
    int e = beg;
    for (; e + 8 <= end; e += 8) {
        int2 r0 = *(const int2*)(fbq + colS[e + 0] + cb);
        int2 r1 = *(const int2*)(fbq + colS[e + 1] + cb);
        int2 r2 = *(const int2*)(fbq + colS[e + 2] + cb);
        int2 r3 = *(const int2*)(fbq + colS[e + 3] + cb);
        int2 r4 = *(const int2*)(fbq + colS[e + 4] + cb);
        int2 r5 = *(const int2*)(fbq + colS[e + 5] + cb);
        int2 r6 = *(const int2*)(fbq + colS[e + 6] + cb);
        int2 r7 = *(const int2*)(fbq + colS[e + 7] + cb);
        float2 l0 = unpack2(r0.x), h0 = unpack2(r0.y);
        float2 l1 = unpack2(r1.x), h1_ = unpack2(r1.y);
        float2 l2 = unpack2(r2.x), h2 = unpack2(r2.y);
        float2 l3 = unpack2(r3.x), h3 = unpack2(r3.y);
        float2 l4 = unpack2(r4.x), h4 = unpack2(r4.y);
        float2 l5 = unpack2(r5.x), h5 = unpack2(r5.y);
        float2 l6 = unpack2(r6.x), h6 = unpack2(r6.y);
        float2 l7 = unpack2(r7.x), h7 = unpack2(r7.y);
        ax += (l0.x + l1.x) + (l2.x + l3.x) + (l4.x + l5.x) + (l6.x + l7.x);
        ay += (l0.y + l1.y) + (l2.y + l3.y) + (l4.y + l5.y) + (l6.y + l7.y);
        az += (h0.x + h1_.x) + (h2.x + h3.x) + (h4.x + h5.x) + (h6.x + h7.x);
        aw += (h0.y + h1_.y) + (h2.y + h3.y) + (h4.y + h5.y) + (h6.y + h7.y);
    }
    for (; e < end; e++) {
        int2 r = *(const int2*)(fbq + colS[e] + cb);
        float2 lo = unpack2(r.x), hi = unpack2(r.y);
        ax += lo.x; ay += lo.y; az += hi.x; aw += hi.y;
    }
    return make_float4(ax, ay, az, aw);
}

// global-col fallback (only the rare block whose span exceeds COL_CAP)
__device__ inline float4 agg6_glb(const int2* __restrict__ fhq,
                                  const int* __restrict__ col,
                                  int beg, int end, int c6) {
    float ax = 0.f, ay = 0.f, az = 0.f, aw = 0.f;
    int e = beg;
    for (; e + 8 <= end; e += 8) {
        int s0 = col[e + 0], s1 = col[e + 1], s2 = col[e + 2], s3 = col[e + 3];
        int s4 = col[e + 4], s5 = col[e + 5], s6 = col[e + 6], s7 = col[e + 7];
        int2 r0 = fhq[(long)s0 * QI + c6], r1 = fhq[(long)s1 * QI + c6];
        int2 r2 = fhq[(long)s2 * QI + c6], r3 = fhq[(long)s3 * QI + c6];
        int2 r4 = fhq[(long)s4 * QI + c6], r5 = fhq[(long)s5 * QI + c6];
        int2 r6 = fhq[(long)s6 * QI + c6], r7 = fhq[(long)s7 * QI + c6];
        float2 l0 = unpack2(r0.x), h0 = unpack2(r0.y);
        float2 l1 = unpack2(r1.x), h1_ = unpack2(r1.y);
        float2 l2 = unpack2(r2.x), h2 = unpack2(r2.y);
        float2 l3 = unpack2(r3.x), h3 = unpack2(r3.y);
        float2 l4 = unpack2(r4.x), h4 = unpack2(r4.y);
        float2 l5 = unpack2(r5.x), h5 = unpack2(r5.y);
        float2 l6 = unpack2(r6.x), h6 = unpack2(r6.y);
        float2 l7 = unpack2(r7.x), h7 = unpack2(r7.y);
        ax += (l0.x + l1.x) + (l2.x + l3.x) + (l4.x + l5.x) + (l6.x + l7.x);
        ay += (l0.y + l1.y) + (l2.y + l3.y) + (l4.y + l5.y) + (l6.y + l7.y);
        az += (h0.x + h1_.x) + (h2.x + h3.x) + (h4.x + h5.x) + (h6.x + h7.x);
        aw += (h0.y + h1_.y) + (h2.y + h3.y) + (h4.y + h5.y) + (h6.y + h7.y);
    }
    for (; e < end; e++) {
        int s = col[e];
        int2 r = fhq[(long)s * QI + c6];
        float2 lo = unpack2(r.x), hi = unpack2(r.y);
        ax += lo.x; ay += lo.y; az += hi.x; aw += hi.y;
    }
    return make_float4(ax, ay, az, aw);
}

// ---------------------------------------------------------------------------
// K1: degree histogram + per-edge rank capture (perm). Hub via ballot.
// ---------------------------------------------------------------------------
__global__ void deg_kernel(const int* __restrict__ dst, int E, int HUB,
                           int* __restrict__ counts, int* __restrict__ perm) {
    int e = blockIdx.x * 256 + threadIdx.x;
    int d = (e < E) ? dst[e] : -1;
    bool isHub = (d == HUB);
    unsigned long long m = __ballot(isHub);
    if (isHub) {
        int lane = threadIdx.x & 63;
        int leader = __ffsll((unsigned long long)m) - 1;
        int base = 0;
        if (lane == leader) base = atomicAdd(&counts[HUB], (int)__popcll(m));
        base = __shfl(base, leader);
        unsigned long long below = m & ((1ull << lane) - 1ull);
        perm[e] = base + (int)__popcll(below);
    } else if (d >= 0) {
        perm[e] = atomicAdd(&counts[d], 1);
    }
}

// ---------------------------------------------------------------------------
// K2: single-kernel scan. Emits rowptr[0..N] and dinv (fused).
// ---------------------------------------------------------------------------
__global__ __launch_bounds__(1024)
void scan_kernel(const int* __restrict__ counts, int N,
                 int* __restrict__ rowptr, float* __restrict__ dinv) {
    int t = threadIdx.x, lane = t & 63, wv = t >> 6;
    int base = blockIdx.x * 1024;
    int pre = 0;
    for (int idx = t; idx < base; idx += 1024) pre += counts[idx];
    #pragma unroll
    for (int off = 32; off; off >>= 1) pre += __shfl_down(pre, off);
    __shared__ int wsA[16];
    __shared__ int preS;
    if (lane == 0) wsA[wv] = pre;
    __syncthreads();
    if (t == 0) {
        int s = 0;
        #pragma unroll
        for (int k = 0; k < 16; k++) s += wsA[k];
        preS = s;
    }
    __syncthreads();
    int blockpre = preS;
    int i = base + t;
    int v = (i < N) ? counts[i] : 0;
    int x = v;
    #pragma unroll
    for (int off = 1; off < 64; off <<= 1) {
        int u = __shfl_up(x, off);
        if (lane >= off) x += u;
    }
    __shared__ int wsum[16];
    if (lane == 63) wsum[wv] = x;
    __syncthreads();
    if (wv == 0 && lane < 16) {
        int w = wsum[lane];
        #pragma unroll
        for (int off = 1; off < 16; off <<= 1) {
            int u = __shfl_up(w, off);
            if (lane >= off) w += u;
        }
        wsum[lane] = w;
    }
    __syncthreads();
    int waveoff = (wv == 0) ? 0 : wsum[wv - 1];
    if (i <= N) rowptr[i] = blockpre + waveoff + x - v;
    if (i < N) {
        float d = (float)v;
        dinv[i] = (d > 0.f) ? rsqrtf(fmaxf(d, 1.f)) : 0.f;
    }
}

// ---------------------------------------------------------------------------
// K3: prep — fused {CSR col fill} + {xh quarters = fp16(dinv*x)} +
// {Wt convert} + {zero a0 hub row}. xh packed as 4 quarter-tables of
// 48 B rows (2.4 MB each, fits one XCD's 4 MB L2).
// ---------------------------------------------------------------------------
__global__ __launch_bounds__(256)
void prep_kernel(const int* __restrict__ src, const int* __restrict__ dst,
                 const int* __restrict__ perm, const int* __restrict__ rowptr,
                 int E,
                 const float* __restrict__ x, const float* __restrict__ dinv,
                 int N,
                 const float* __restrict__ W2a, const float* __restrict__ W2b,
                 int* __restrict__ col, int2* __restrict__ xh,
                 __half* __restrict__ Wta, __half* __restrict__ Wtb,
                 float* __restrict__ a0hub, int gfill, int gconv, int gwt) {
    int b = blockIdx.x;
    if (b < gfill) {
        int e = b * 256 + threadIdx.x;
        if (e >= E) return;
        int d = dst[e];
        col[rowptr[d] + perm[e]] = src[e];
    } else if (b < gfill + gconv) {
        int i = (b - gfill) * 256 + threadIdx.x;
        if (i >= N * 24) return;
        int n = i / 24, g = i % 24;
        float dn = dinv[n];
        float4 a = ((const float4*)x)[i];
        int2 v = pack4(a.x * dn, a.y * dn, a.z * dn, a.w * dn);
        xh[(size_t)(g / QI) * N * QI + (size_t)n * QI + (g % QI)] = v;
    } else if (b < gfill + gconv + gwt) {
        int i = (b - gfill - gconv) * 256 + threadIdx.x;
        if (i >= FD * FD) return;
        int n = i / FD, k = i % FD;
        Wta[i] = __float2half(W2a[k * FD + n]);
        Wtb[i] = __float2half(W2b[k * FD + n]);
    } else {
        int i = threadIdx.x;
        if (i < FD) a0hub[i] = 0.f;
    }
}

// ---------------------------------------------------------------------------
// Quarter pull+hub kernels, XCD-pinned: quarter q is processed only by blocks
// with blockIdx%8 in {2q, 2q+1} (round-robin block->XCD => each XCD's L2
// caches one 2.4 MB quarter). Block 384 thr = (c6 0..5, y 0..63); 64 nodes
// per tile; block col span staged in LDS (pre-scaled byte offsets).
// Grid = 8*T + 128 (T = ceil(Gq/2)); last 128 blocks = hub (2048 streams per
// quarter, same edge chunking as before -> per-stream partials identical).
// ---------------------------------------------------------------------------
__global__ __launch_bounds__(384)
void pullq32(const int2* __restrict__ fh, const float* __restrict__ dinv,
             const int* __restrict__ rowptr, const int* __restrict__ col,
             int N, int HUB, int T, int Gq,
             float* __restrict__ out, float* __restrict__ hubdest) {
    __shared__ int colS[COL_CAP];
    __shared__ float4 red[64][6];
    int t = threadIdx.x;
    int c = t % 6, y = t / 6;
    int b = blockIdx.x;
    if (b < 8 * T) {
        int s = b & 7, q = s >> 1;
        int tile = (b >> 3) * 2 + (s & 1);
        if (tile >= Gq) return;
        const int2* fhq = fh + (size_t)q * N * QI;
        int n0 = tile * 64;
        int nend = min(n0 + 64, N);
        int beg0 = rowptr[n0];
        int span = rowptr[nend] - beg0;
        bool staged = (span <= COL_CAP);
        if (staged) {
            for (int i = t; i < span; i += 384) colS[i] = col[beg0 + i] * 48;
            __syncthreads();
        }
        int n = n0 + y;
        if (n < N && n != HUB) {
            int beg = rowptr[n], end = rowptr[n + 1];
            float4 a = staged
                ? agg6_lds((const char*)fhq, colS, beg - beg0, end - beg0, c)
                : agg6_glb(fhq, col, beg, end, c);
            float dn = dinv[n];
            ((float4*)out)[(long)n * 24 + q * 6 + c] =
                make_float4(a.x * dn, a.y * dn, a.z * dn, a.w * dn);
        }
    } else {
        int hb = b - 8 * T;                       // [0,128)
        int q = (hb & 7) >> 1;
        int sb = (hb >> 3) * 2 + (hb & 1);        // [0,32) per quarter
        const int2* fhq = fh + (size_t)q * N * QI;
        int beg = rowptr[HUB], end = rowptr[HUB + 1];
        int deg = end - beg;
        int chunk = (deg + 2047) / 2048;
        int sid = sb * 64 + y;
        int e = beg + sid * chunk;
        int e1 = min(e + chunk, end);
        float ax = 0.f, ay = 0.f, az = 0.f, aw = 0.f;
        for (; e + 4 <= e1; e += 4) {
            int s0 = col[e + 0], s1 = col[e + 1], s2 = col[e + 2], s3 = col[e + 3];
            int2 r0 = fhq[(long)s0 * QI + c], r1 = fhq[(long)s1 * QI + c];
            int2 r2 = fhq[(long)s2 * QI + c], r3 = fhq[(long)s3 * QI + c];
            float2 l0 = unpack2(r0.x), h0 = unpack2(r0.y);
            float2 l1 = unpack2(r1.x), h1_ = unpack2(r1.y);
            float2 l2 = unpack2(r2.x), h2 = unpack2(r2.y);
            float2 l3 = unpack2(r3.x), h3 = unpack2(r3.y);
            ax += (l0.x + l1.x) + (l2.x + l3.x);
            ay += (l0.y + l1.y) + (l2.y + l3.y);
            az += (h0.x + h1_.x) + (h2.x + h3.x);
            aw += (h0.y + h1_.y) + (h2.y + h3.y);
        }
        for (; e < e1; e++) {
            int s = col[e];
            int2 r = fhq[(long)s * QI + c];
            float2 lo = unpack2(r.x), hi = unpack2(r.y);
            ax += lo.x; ay += lo.y; az += hi.x; aw += hi.y;
        }
        red[y][c] = make_float4(ax, ay, az, aw);
        __syncthreads();
        if (y == 0) {
            float4 tt = red[0][c];
            #pragma unroll
            for (int k = 1; k < 64; k++) {
                float4 u = red[k][c];
                tt.x += u.x; tt.y += u.y; tt.z += u.z; tt.w += u.w;
            }
            float dh = dinv[HUB];
            float* o = hubdest + q * 24 + c * 4;
            unsafeAtomicAdd(o + 0, tt.x * dh);
            unsafeAtomicAdd(o + 1, tt.y * dh);
            unsafeAtomicAdd(o + 2, tt.z * dh);
            unsafeAtomicAdd(o + 3, tt.w * dh);
        }
    }
}

__global__ __launch_bounds__(384)
void pullq16(const int2* __restrict__ fh, const float* __restrict__ dinv,
             const int* __restrict__ rowptr, const int* __restrict__ col,
             int N, int HUB, int T, int Gq,
             int2* __restrict__ out16, float* __restrict__ hubdest) {
    __shared__ int colS[COL_CAP];
    __shared__ float4 red[64][6];
    int t = threadIdx.x;
    int c = t % 6, y = t / 6;
    int b = blockIdx.x;
    if (b < 8 * T) {
        int s = b & 7, q = s >> 1;
        int tile = (b >> 3) * 2 + (s & 1);
        if (tile >= Gq) return;
        const int2* fhq = fh + (size_t)q * N * QI;
        int n0 = tile * 64;
        int nend = min(n0 + 64, N);
        int beg0 = rowptr[n0];
        int span = rowptr[nend] - beg0;
        bool staged = (span <= COL_CAP);
        if (staged) {
            for (int i = t; i < span; i += 384) colS[i] = col[beg0 + i] * 48;
            __syncthreads();
        }
        int n = n0 + y;
        if (n < N && n != HUB) {
            int beg = rowptr[n], end = rowptr[n + 1];
            float4 a = staged
                ? agg6_lds((const char*)fhq, colS, beg - beg0, end - beg0, c)
                : agg6_glb(fhq, col, beg, end, c);
            float dn = dinv[n];
            out16[(long)n * 24 + q * 6 + c] =
                pack4(a.x * dn, a.y * dn, a.z * dn, a.w * dn);
        }
    } else {
        int hb = b - 8 * T;
        int q = (hb & 7) >> 1;
        int sb = (hb >> 3) * 2 + (hb & 1);
        const int2* fhq = fh + (size_t)q * N * QI;
        int beg = rowptr[HUB], end = rowptr[HUB + 1];
        int deg = end - beg;
        int chunk = (deg + 2047) / 2048;
        int sid = sb * 64 + y;
        int e = beg + sid * chunk;
        int e1 = min(e + chunk, end);
        float ax = 0.f, ay = 0.f, az = 0.f, aw = 0.f;
        for (; e + 4 <= e1; e += 4) {
            int s0 = col[e + 0], s1 = col[e + 1], s2 = col[e + 2], s3 = col[e + 3];
            int2 r0 = fhq[(long)s0 * QI + c], r1 = fhq[(long)s1 * QI + c];
            int2 r2 = fhq[(long)s2 * QI + c], r3 = fhq[(long)s3 * QI + c];
            float2 l0 = unpack2(r0.x), h0 = unpack2(r0.y);
            float2 l1 = unpack2(r1.x), h1_ = unpack2(r1.y);
            float2 l2 = unpack2(r2.x), h2 = unpack2(r2.y);
            float2 l3 = unpack2(r3.x), h3 = unpack2(r3.y);
            ax += (l0.x + l1.x) + (l2.x + l3.x);
            ay += (l0.y + l1.y) + (l2.y + l3.y);
            az += (h0.x + h1_.x) + (h2.x + h3.x);
            aw += (h0.y + h1_.y) + (h2.y + h3.y);
        }
        for (; e < e1; e++) {
            int s = col[e];
            int2 r = fhq[(long)s * QI + c];
            float2 lo = unpack2(r.x), hi = unpack2(r.y);
            ax += lo.x; ay += lo.y; az += hi.x; aw += hi.y;
        }
        red[y][c] = make_float4(ax, ay, az, aw);
        __syncthreads();
        if (y == 0) {
            float4 tt = red[0][c];
            #pragma unroll
            for (int k = 1; k < 64; k++) {
                float4 u = red[k][c];
                tt.x += u.x; tt.y += u.y; tt.z += u.z; tt.w += u.w;
            }
            float dh = dinv[HUB];
            float* o = hubdest + q * 24 + c * 4;
            unsafeAtomicAdd(o + 0, tt.x * dh);
            unsafeAtomicAdd(o + 1, tt.y * dh);
            unsafeAtomicAdd(o + 2, tt.z * dh);
            unsafeAtomicAdd(o + 3, tt.w * dh);
        }
    }
}

// ---------------------------------------------------------------------------
// gemm96_h — h1 quarters = fp16(dinv*relu(A@W1+b1)). Math unchanged
// (verified); only the output indexing targets quarter-tables.
// ---------------------------------------------------------------------------
__global__ __launch_bounds__(192)
void gemm96_h(const float* __restrict__ A, const float* __restrict__ W,
              const float* __restrict__ bias, const float* __restrict__ dinv,
              int2* __restrict__ outq, int N) {
    __shared__ __half Wl[FD * FD];       // 18432 B
    __shared__ float As[64 * 100];       // 25600 B
    int t = threadIdx.y * 24 + threadIdx.x;
    {   // stage W fp32 -> fp16
        const float4* W4 = (const float4*)W;
        #pragma unroll 4
        for (int i = t; i < FD * 24; i += 192) {
            float4 w = W4[i];
            *(int2*)&Wl[i * 4] = pack4(w.x, w.y, w.z, w.w);
        }
    }
    int row0 = blockIdx.x * 64;
    int nrows = min(64, N - row0);
    {
        const float4* A4 = (const float4*)(A + (long)row0 * FD);
        for (int i = t; i < nrows * 24; i += 192) {
            int r = i / 24, g = i % 24;
            *(float4*)&As[r * 100 + g * 4] = A4[i];
        }
    }
    __syncthreads();
    int c = threadIdx.x, y = threadIdx.y;
    float acc[8][4];
    #pragma unroll
    for (int j = 0; j < 8; j++)
        #pragma unroll
        for (int i = 0; i < 4; i++) acc[j][i] = 0.f;
    for (int kk = 0; kk < FD; kk += 4) {
        float4 w0 = lds_w4(Wl, kk + 0, 4 * c);
        float4 w1 = lds_w4(Wl, kk + 1, 4 * c);
        float4 w2 = lds_w4(Wl, kk + 2, 4 * c);
        float4 w3 = lds_w4(Wl, kk + 3, 4 * c);
        #pragma unroll
        for (int j = 0; j < 8; j++) {
            float4 a = *(const float4*)&As[(y + 8 * j) * 100 + kk];
            acc[j][0] = fmaf(a.x, w0.x, fmaf(a.y, w1.x, fmaf(a.z, w2.x, fmaf(a.w, w3.x, acc[j][0]))));
            acc[j][1] = fmaf(a.x, w0.y, fmaf(a.y, w1.y, fmaf(a.z, w2.y, fmaf(a.w, w3.y, acc[j][1]))));
            acc[j][2] = fmaf(a.x, w0.z, fmaf(a.y, w1.z, fmaf(a.z, w2.z, fmaf(a.w, w3.z, acc[j][2]))));
            acc[j][3] = fmaf(a.x, w0.w, fmaf(a.y, w1.w, fmaf(a.z, w2.w, fmaf(a.w, w3.w, acc[j][3]))));
        }
    }
    float4 b4 = *(const float4*)&bias[4 * c];
    #pragma unroll
    for (int j = 0; j < 8; j++) {
        int r = y + 8 * j;
        if (r < nrows) {
            float vx = fmaxf(acc[j][0] + b4.x, 0.f);
            float vy = fmaxf(acc[j][1] + b4.y, 0.f);
            float vz = fmaxf(acc[j][2] + b4.z, 0.f);
            float vw = fmaxf(acc[j][3] + b4.w, 0.f);
            float dr = dinv[row0 + r];
            int2 v = pack4(vx * dr, vy * dr, vz * dr, vw * dr);
            long n = row0 + r;
            outq[(size_t)(c / QI) * N * QI + (size_t)n * QI + (c % QI)] = v;
        }
    }
}

// ---------------------------------------------------------------------------
// mfma_dual — mu = A@Wa+ba, ls = A@Wb+bb via v_mfma_f32_16x16x32_f16.
// Unchanged (verified). a1h is full-row layout (pullq16 writes n*24+q*6+c).
// ---------------------------------------------------------------------------
__global__ __launch_bounds__(256)
void mfma_dual(const __half* __restrict__ a1h, const float* __restrict__ hubacc,
               const __half* __restrict__ Wta, const __half* __restrict__ Wtb,
               const float* __restrict__ ba, const float* __restrict__ bb,
               float* __restrict__ mu, float* __restrict__ ls, int N, int HUB) {
    __shared__ __half WtaL[FD * FD];     // 18432 B
    __shared__ __half WtbL[FD * FD];     // 18432 B
    int t = threadIdx.x;
    {
        const int4* sa = (const int4*)Wta;
        const int4* sb = (const int4*)Wtb;
        int4* da = (int4*)WtaL;
        int4* db = (int4*)WtbL;
        #pragma unroll
        for (int i = t; i < FD * FD / 8; i += 256) { da[i] = sa[i]; db[i] = sb[i]; }
    }
    __syncthreads();
    int wv = t >> 6, lane = t & 63;
    int m = lane & 15, q = lane >> 4;
    long row0 = (long)blockIdx.x * 64 + wv * 16;

    const f16x8* arow = (const f16x8*)&a1h[(row0 + m) * FD + q * 8];
    f16x8 A0 = arow[0];
    f16x8 A1 = arow[4];
    f16x8 A2 = arow[8];
    if (row0 + m == HUB) {   // hub row: a1h[HUB] never written; build from fp32
        A0 = pack8h(hubacc + q * 8);
        A1 = pack8h(hubacc + 32 + q * 8);
        A2 = pack8h(hubacc + 64 + q * 8);
    }

    #pragma unroll
    for (int nt = 0; nt < 6; nt++) {
        int n0 = nt * 16;
        const f16x8* brA = (const f16x8*)&WtaL[(n0 + m) * FD + q * 8];
        const f16x8* brB = (const f16x8*)&WtbL[(n0 + m) * FD + q * 8];
        f32x4 acca = {0.f, 0.f, 0.f, 0.f};
        f32x4 accb = {0.f, 0.f, 0.f, 0.f};
        acca = __builtin_amdgcn_mfma_f32_16x16x32_f16(A0, brA[0], acca, 0, 0, 0);
        acca = __builtin_amdgcn_mfma_f32_16x16x32_f16(A1, brA[4], acca, 0, 0, 0);
        acca = __builtin_amdgcn_mfma_f32_16x16x32_f16(A2, brA[8], acca, 0, 0, 0);
        accb = __builtin_amdgcn_mfma_f32_16x16x32_f16(A0, brB[0], accb, 0, 0, 0);
        accb = __builtin_amdgcn_mfma_f32_16x16x32_f16(A1, brB[4], accb, 0, 0, 0);
        accb = __builtin_amdgcn_mfma_f32_16x16x32_f16(A2, brB[8], accb, 0, 0, 0);
        float bva = ba[n0 + m];
        float bvb = bb[n0 + m];
        #pragma unroll
        for (int r = 0; r < 4; r++) {
            long row = row0 + q * 4 + r;
            if (row < N) {
                mu[row * FD + n0 + m] = acca[r] + bva;
                ls[row * FD + n0 + m] = accb[r] + bvb;
            }
        }
    }
}

// ---------------------------------------------------------------------------
// Launch. 8 dispatches: memset, deg, scan, prep, pullq32, gemm96_h, pullq16,
// mfma_dual. Feature tables split into four 2.4 MB quarters, each pinned to
// an XCD pair via blockIdx%8 swizzle -> gathers become L2 hits.
//   xh (4 quarters)  = fp16(dinv*x)  -> mu slot, lower 9.6 MB
//   a0               = agg(xh)       -> ls slot (fp32; hub row zeroed by prep)
//   h1 (4 quarters)  = fp16 layer-1  -> mu slot, upper 9.6 MB  (a0 dead)
//   a1h (full rows)  = fp16 agg(h1)  -> ws (hub row via hubacc in mfma_dual)
//   mu,ls            = MFMA dual-gemm(a1h) -> d_out
// ws: [counts N][hubacc 96][perm E][rowptr N+1][col E][dinv N]
//     [Wta][Wtb][a1h (N+64)x96 h]  ~= 17.5 MB
// ---------------------------------------------------------------------------
extern "C" void kernel_launch(void* const* d_in, const int* in_sizes, int n_in,
                              void* d_out, int out_size, void* d_ws, size_t ws_size,
                              hipStream_t stream) {
    const float* x   = (const float*)d_in[0];
    const float* W1  = (const float*)d_in[1];
    const float* b1  = (const float*)d_in[2];
    const float* W2a = (const float*)d_in[3];
    const float* b2a = (const float*)d_in[4];
    const float* W2b = (const float*)d_in[5];
    const float* b2b = (const float*)d_in[6];
    const int*   ei  = (const int*)d_in[7];

    const int N   = in_sizes[0] / FD;
    const int E   = in_sizes[7] / 2;
    const int HUB = N - 1;
    const int* src = ei;
    const int* dst = ei + E;
    const int NB  = (N + 1023) / 1024;

    int* counts   = (int*)d_ws;                 // N
    float* hubacc = (float*)(counts + N);       // 96
    int* perm     = (int*)(hubacc + FD);        // E
    int* rowptr   = perm + E;                   // N+1
    int* col      = rowptr + (N + 1);           // E
    float* dinv   = (float*)(col + E);          // N
    uintptr_t p = (uintptr_t)(dinv + N);
    p = (p + 15) & ~(uintptr_t)15;
    __half* Wta = (__half*)p;                   // FD*FD
    __half* Wtb = Wta + FD * FD;                // FD*FD
    __half* a1h = Wtb + FD * FD;                // (N+64)*FD halves, 16B-aligned

    float* mu_slot = (float*)d_out;
    float* ls_slot = (float*)d_out + (size_t)N * FD;
    int2* xh = (int2*)mu_slot;                       // 9.6 MB (4 quarters)
    int2* h1 = (int2*)mu_slot + (size_t)N * 24;      // 9.6 MB (4 quarters)
    float* a0 = ls_slot;
    float* a0hub = a0 + (size_t)HUB * FD;

    // zero counts + hubacc (contiguous)
    (void)hipMemsetAsync(counts, 0, ((size_t)N + FD) * sizeof(int), stream);

    deg_kernel <<<dim3((E + 255) / 256), dim3(256), 0, stream>>>(dst, E, HUB,
                                                                 counts, perm);
    scan_kernel<<<dim3(NB), dim3(1024), 0, stream>>>(counts, N, rowptr, dinv);

    int gfill = (E + 255) / 256;
    int gconv = (N * 24 + 255) / 256;
    int gwt   = (FD * FD + 255) / 256;
    prep_kernel<<<dim3(gfill + gconv + gwt + 1), dim3(256), 0, stream>>>(
        src, dst, perm, rowptr, E, x, dinv, N, W2a, W2b,
        col, xh, Wta, Wtb, a0hub, gfill, gconv, gwt);

    int Gq = (N + 63) / 64;
    int T  = (Gq + 1) / 2;
    int gemmG = (N + 63) / 64;
    dim3 gemmB(24, 8);

    // layer 1 (quarter pulls + hub merged; hub accumulates into a0 hub row)
    pullq32<<<dim3(8 * T + 128), dim3(384), 0, stream>>>(
        xh, dinv, rowptr, col, N, HUB, T, Gq, a0, a0hub);
    gemm96_h<<<dim3(gemmG), gemmB, 0, stream>>>(a0, W1, b1, dinv, h1, N);

    // layer 2 (quarter pulls + hub merged; hub row via hubacc in mfma)
    pullq16<<<dim3(8 * T + 128), dim3(384), 0, stream>>>(
        h1, dinv, rowptr, col, N, HUB, T, Gq, (int2*)a1h, hubacc);
    mfma_dual<<<dim3(gemmG), dim3(256), 0, stream>>>(a1h, hubacc, Wta, Wtb,
                                                     b2a, b2b, mu_slot, ls_slot,
                                                     N, HUB);
}